// Round 4
// baseline (261.677 us; speedup 1.0000x reference)
//
#include <hip/hip_runtime.h>

// 24-qubit brickwork circuit, register-resident gates, 32KB split-LDS transposes.
// State: flat index i in [0, 2^24), wire w <-> bit (23-w).
// Gate on wires (w,w+1): p1 = 22-w, p0 = 23-w. M[v][u] = G[u0,v0,u1,v1],
// u = (u0<<1)|u1, u0 = bit p0, u1 = bit p1 (v likewise).
//
// Each thread holds 64 amps as v2f w[32] (vector bit = reg bit 0).
// Layout = assignment of 6 j-bits to reg bits r0..r5 + 8 j-bits to t0..t7.
// Transitions: 2-stage transpose through a 8192-float buffer, split on a
// j-bit that sits at the SAME reg position in both layouts (in-place safe).
// Bank analysis: buffer bank bits = SWZ(j) bits 0..4 (split bits are >=5),
// identical to the round-2 full-tile patterns that measured 0 conflicts.

typedef float v2f __attribute__((ext_vector_type(2)));

#define SWZ(j) ((j) ^ (((j) >> 6) & 15) ^ ((((j) >> 10) & 1) << 4))
#define DEL(x, S) (((x) & ((1 << (S)) - 1)) | (((x) >> ((S) + 1)) << (S)))
#define AMP_LD(r) (((r) & 1) ? w[(r) >> 1].y : w[(r) >> 1].x)
#define AMP_ST(r, val) do { if ((r) & 1) w[(r) >> 1].y = (val); else w[(r) >> 1].x = (val); } while (0)

// Gate acting on reg bits B0 (holds p1 / u1) and B1 (holds p0 / u0).
template<int B0, int B1>
__device__ __forceinline__ void gate_v2(v2f w[32], const float* __restrict__ g) {
  float m[16];
#pragma unroll
  for (int vv = 0; vv < 4; ++vv)
#pragma unroll
    for (int uu = 0; uu < 4; ++uu)
      m[vv * 4 + uu] = g[(uu >> 1) * 8 + (vv >> 1) * 4 + (uu & 1) * 2 + (vv & 1)];
  if constexpr (B0 != 0 && B1 != 0) {
    constexpr int S1 = 1 << B0, S0 = 1 << B1;  // strides: u1-bit, u0-bit
#pragma unroll
    for (int b = 0; b < 64; ++b) {
      if (b & (S0 | S1 | 1)) continue;
      v2f A0 = w[b >> 1], A1 = w[(b + S1) >> 1], A2 = w[(b + S0) >> 1], A3 = w[(b + S0 + S1) >> 1];
      w[b >> 1]             = m[0] * A0 + m[1] * A1 + m[2] * A2 + m[3] * A3;
      w[(b + S1) >> 1]      = m[4] * A0 + m[5] * A1 + m[6] * A2 + m[7] * A3;
      w[(b + S0) >> 1]      = m[8] * A0 + m[9] * A1 + m[10] * A2 + m[11] * A3;
      w[(b + S0 + S1) >> 1] = m[12] * A0 + m[13] * A1 + m[14] * A2 + m[15] * A3;
    }
  } else if constexpr (B0 == 0) {
    constexpr int S0 = 1 << B1;
    v2f m04 = {m[0], m[4]}, m15 = {m[1], m[5]}, m26 = {m[2], m[6]}, m37 = {m[3], m[7]};
    v2f m8c = {m[8], m[12]}, m9d = {m[9], m[13]}, mae = {m[10], m[14]}, mbf = {m[11], m[15]};
#pragma unroll
    for (int b = 0; b < 64; ++b) {
      if (b & (S0 | 1)) continue;
      v2f p = w[b >> 1], q = w[(b + S0) >> 1];  // p={a0,a1}, q={a2,a3}
      w[b >> 1]        = m04 * p.x + m15 * p.y + m26 * q.x + m37 * q.y;  // {o0,o1}
      w[(b + S0) >> 1] = m8c * p.x + m9d * p.y + mae * q.x + mbf * q.y;  // {o2,o3}
    }
  } else {  // B1 == 0
    constexpr int S1 = 1 << B0;
    v2f m08 = {m[0], m[8]}, m19 = {m[1], m[9]}, m2a = {m[2], m[10]}, m3b = {m[3], m[11]};
    v2f m4c = {m[4], m[12]}, m5d = {m[5], m[13]}, m6e = {m[6], m[14]}, m7f = {m[7], m[15]};
#pragma unroll
    for (int b = 0; b < 64; ++b) {
      if (b & (S1 | 1)) continue;
      v2f p = w[b >> 1], q = w[(b + S1) >> 1];  // p={a0,a2}, q={a1,a3}
      w[b >> 1]        = m08 * p.x + m19 * q.x + m2a * p.y + m3b * q.y;  // {o0,o2}
      w[(b + S1) >> 1] = m4c * p.x + m5d * q.x + m6e * p.y + m7f * q.y;  // {o1,o3}
    }
  }
}

// layout formulas: j(t, r)
// pass1: B r=[j8..j13], t=j0..7
#define JB1(t, r) ((t) | ((r) << 8))
// pass1: M r=[j8,j4,j5,j6,j7,j9], t0..3=j0..3, t4..7=j10..13
#define JM1(t, r) (((t) & 15) | ((((r) >> 1) & 15) << 4) | (((r) & 1) << 8) | (((r) >> 5) << 9) | (((t) >> 4) << 10))
// pass1: A r=[j0,j1,j5,j2,j3,j4], t=j6..13
#define JA1(t, r) (((r) & 3) | ((((r) >> 3) & 7) << 2) | ((((r) >> 2) & 1) << 5) | ((t) << 6))
// pass1: W r=[j6,j7,j5,j8,j9,j10], t0..4=j0..4, t5..7=j11..13
#define JW1(t, r) (((t) & 31) | ((((r) >> 2) & 1) << 5) | (((r) & 1) << 6) | ((((r) >> 1) & 1) << 7) | ((((r) >> 3) & 7) << 8) | (((t) >> 5) << 11))
// pass2: F r=[j0,j1,j10,j11,j12,j13], t=j2..9
#define JF(t, r)  (((r) & 3) | ((t) << 2) | (((r) >> 2) << 10))
// pass2a: V r=[j7,j8,j10,j9,j11,j12], t0..6=j0..6, t7=j13
#define JV(t, r)  (((t) & 127) | (((r) & 1) << 7) | ((((r) >> 1) & 1) << 8) | ((((r) >> 3) & 1) << 9) | ((((r) >> 2) & 1) << 10) | ((((r) >> 4) & 3) << 11) | (((t) >> 7) << 13))
// pass2b: W r=[j8,j5,j6,j7,j9,j10], t0..4=j0..4, t5..7=j11..13
#define JW2(t, r) (((t) & 31) | ((((r) >> 1) & 7) << 5) | (((r) & 1) << 8) | ((((r) >> 4) & 3) << 9) | (((t) >> 5) << 11))

// 2-stage in-place transpose. Split j-bit S sits at reg position RBIT in
// BOTH layouts, so read-set(stage) == write-set(stage) (in-place safe).
#define TRANS(JW, JR, S, RBIT)                                        \
  do {                                                                \
    _Pragma("unroll")                                                 \
    for (int r = 0; r < 64; ++r) if ((((r) >> (RBIT)) & 1) == 0)      \
      buf[DEL(SWZ(JW(t, r)), S)] = AMP_LD(r);                         \
    __syncthreads();                                                  \
    _Pragma("unroll")                                                 \
    for (int r = 0; r < 64; ++r) if ((((r) >> (RBIT)) & 1) == 0)      \
      AMP_ST(r, buf[DEL(SWZ(JR(t, r)), S)]);                          \
    __syncthreads();                                                  \
    _Pragma("unroll")                                                 \
    for (int r = 0; r < 64; ++r) if ((((r) >> (RBIT)) & 1) == 1)      \
      buf[DEL(SWZ(JW(t, r)), S)] = AMP_LD(r);                         \
    __syncthreads();                                                  \
    _Pragma("unroll")                                                 \
    for (int r = 0; r < 64; ++r) if ((((r) >> (RBIT)) & 1) == 1)      \
      AMP_ST(r, buf[DEL(SWZ(JR(t, r)), S)]);                          \
    __syncthreads();                                                  \
  } while (0)

// ---------------- Pass 1: init + 24 gates on bits 0..13 (wires 10..23) -------
__global__ __launch_bounds__(256, 4) void k_pass1(
    const float* __restrict__ states, const float* __restrict__ gates,
    float* __restrict__ out) {
  __shared__ float buf[8192];
  const int t = threadIdx.x;
  const int b = blockIdx.x;  // global bits 14..23 (wires 9..0)

  {
    float p = 1.f;
    for (int k = 0; k < 8; ++k) p *= states[(23 - k) * 2 + ((t >> k) & 1)];
    buf[t] = p;  // sLo over j0..7 (wires 23..16)
    if (t < 64) {
      float q = 1.f;
      for (int k = 0; k < 6; ++k) q *= states[(15 - k) * 2 + ((t >> k) & 1)];
      buf[256 + t] = q;  // sHi over j8..13 (wires 15..10)
    }
  }
  float pref = 1.f;
  for (int k = 0; k < 10; ++k) pref *= states[(9 - k) * 2 + ((b >> k) & 1)];
  __syncthreads();

  v2f w[32];
  const float plT = pref * buf[t];
#pragma unroll
  for (int i = 0; i < 32; ++i) {
    w[i].x = plT * buf[256 + 2 * i];
    w[i].y = plT * buf[256 + 2 * i + 1];
  }
  __syncthreads();  // protect buf before transition writes

  // Phase B (r=[j8..13]): g5(12,13) g6(10,11) g7(8,9) g17(11,12) g18(9,10) g29(10,11)
  gate_v2<4, 5>(w, gates + 16 * 5);
  gate_v2<2, 3>(w, gates + 16 * 6);
  gate_v2<0, 1>(w, gates + 16 * 7);
  gate_v2<3, 4>(w, gates + 16 * 17);
  gate_v2<1, 2>(w, gates + 16 * 18);
  gate_v2<2, 3>(w, gates + 16 * 29);
  TRANS(JB1, JM1, 8, 0);  // split j8 @ r0
  // Phase M (r=[j8,j4,j5,j6,j7,j9]): g8(6,7) g9(4,5) g19(7,8) g20(5,6) g30(8,9) g31(6,7)
  gate_v2<3, 4>(w, gates + 16 * 8);
  gate_v2<1, 2>(w, gates + 16 * 9);
  gate_v2<4, 0>(w, gates + 16 * 19);
  gate_v2<2, 3>(w, gates + 16 * 20);
  gate_v2<0, 5>(w, gates + 16 * 30);
  gate_v2<3, 4>(w, gates + 16 * 31);
  TRANS(JM1, JA1, 5, 2);  // split j5 @ r2
  // Phase A (r=[j0,j1,j5,j2,j3,j4]): g10(2,3) g11(0,1) g21(3,4) g22(1,2)
  //                                   g32(4,5) g33(2,3) g34(0,1) g44(3,4) g45(1,2)
  gate_v2<3, 4>(w, gates + 16 * 10);
  gate_v2<0, 1>(w, gates + 16 * 11);
  gate_v2<4, 5>(w, gates + 16 * 21);
  gate_v2<1, 3>(w, gates + 16 * 22);
  gate_v2<5, 2>(w, gates + 16 * 32);
  gate_v2<3, 4>(w, gates + 16 * 33);
  gate_v2<0, 1>(w, gates + 16 * 34);
  gate_v2<4, 5>(w, gates + 16 * 44);
  gate_v2<1, 3>(w, gates + 16 * 45);
  TRANS(JA1, JW1, 5, 2);  // split j5 @ r2
  // Phase W (r=[j6,j7,j5,j8,j9,j10]): g41(9,10) g42(7,8) g43(5,6)
  gate_v2<4, 5>(w, gates + 16 * 41);
  gate_v2<1, 3>(w, gates + 16 * 42);
  gate_v2<2, 0>(w, gates + 16 * 43);

  const long long ob = ((long long)b) << 14;
#pragma unroll
  for (int r = 0; r < 64; ++r) out[ob | JW1(t, r)] = AMP_LD(r);  // 2x128B runs/inst
}

// ---------------- Pass 2a: 8 gates, tile = global {0..5} u {10..17} ----------
// local j: j0..5 = global 0..5, j6..13 = global 10..17
__global__ __launch_bounds__(256, 4) void k_pass2a(
    const float* __restrict__ gates, float* __restrict__ out) {
  __shared__ float buf[8192];
  const int t = threadIdx.x;
  const int b = blockIdx.x;
  const long long base0 = (((long long)(b >> 4)) << 18) | ((long long)(b & 15) << 6);

  v2f w[32];
#pragma unroll
  for (int c = 0; c < 16; ++c) {  // F layout load, 256B runs
    float4 x = *(const float4*)(&out[base0 + ((t & 15) << 2) + ((t >> 4) << 10) + ((long long)c << 14)]);
    w[2 * c] = (v2f){x.x, x.y};
    w[2 * c + 1] = (v2f){x.z, x.w};
  }
  // Phase F (r=[j0,j1,j10..13]): g3(12,13)
  gate_v2<4, 5>(w, gates + 16 * 3);
  TRANS(JF, JV, 10, 2);  // split j10 @ r2
  // Phase V (r=[j7,j8,j10,j9,j11,j12]): g4(10,11) g15(11,12) g16(9,10)
  //                                      g27(10,11) g28(8,9) g39(9,10) g40(7,8)
  gate_v2<2, 4>(w, gates + 16 * 4);
  gate_v2<4, 5>(w, gates + 16 * 15);
  gate_v2<3, 2>(w, gates + 16 * 16);
  gate_v2<2, 4>(w, gates + 16 * 27);
  gate_v2<1, 3>(w, gates + 16 * 28);
  gate_v2<3, 2>(w, gates + 16 * 39);
  gate_v2<0, 1>(w, gates + 16 * 40);

#pragma unroll
  for (int r = 0; r < 64; ++r) {  // V-layout store, 256B runs
    const int j = JV(t, r);
    out[base0 | (((long long)(j >> 6)) << 10) | (j & 63)] = AMP_LD(r);
  }
}

// ---------------- Pass 2b: 14 gates, tile = global {0..4} u {15..23} ---------
// local j: j0..4 = global 0..4, j5..13 = global 15..23
__global__ __launch_bounds__(256, 4) void k_pass2b(
    const float* __restrict__ gates, float* __restrict__ out) {
  __shared__ float buf[8192];
  const int t = threadIdx.x;
  const int b = blockIdx.x;  // global bits 5..14

  v2f w[32];
#pragma unroll
  for (int c = 0; c < 16; ++c) {  // F layout load, 128B runs
    float4 x = *(const float4*)(&out[((t & 7) << 2) + ((long long)b << 5) + ((t >> 3) << 15) + ((long long)c << 20)]);
    w[2 * c] = (v2f){x.x, x.y};
    w[2 * c + 1] = (v2f){x.z, x.w};
  }
  // Phase F (r=[j0,j1,j10..13]): g0(12,13) g1(10,11) g12(11,12) g23(12,13)
  gate_v2<4, 5>(w, gates + 16 * 0);
  gate_v2<2, 3>(w, gates + 16 * 1);
  gate_v2<3, 4>(w, gates + 16 * 12);
  gate_v2<4, 5>(w, gates + 16 * 23);
  TRANS(JF, JB1, 10, 2);  // split j10 @ r2
  // Phase B (r=[j8..13]): g2(8,9) g13(9,10) g24(10,11) g35(11,12)
  gate_v2<0, 1>(w, gates + 16 * 2);
  gate_v2<1, 2>(w, gates + 16 * 13);
  gate_v2<2, 3>(w, gates + 16 * 24);
  gate_v2<3, 4>(w, gates + 16 * 35);
  TRANS(JB1, JW2, 8, 0);  // split j8 @ r0
  // Phase W (r=[j8,j5,j6,j7,j9,j10]): g14(7,8) g25(8,9) g26(6,7)
  //                                    g36(9,10) g37(7,8) g38(5,6)
  gate_v2<3, 0>(w, gates + 16 * 14);
  gate_v2<0, 4>(w, gates + 16 * 25);
  gate_v2<2, 3>(w, gates + 16 * 26);
  gate_v2<4, 5>(w, gates + 16 * 36);
  gate_v2<3, 0>(w, gates + 16 * 37);
  gate_v2<1, 2>(w, gates + 16 * 38);

#pragma unroll
  for (int r = 0; r < 64; ++r) {  // W-layout store, 2x128B runs/inst
    const int j = JW2(t, r);
    out[(((long long)(j >> 5)) << 15) | ((long long)b << 5) | (j & 31)] = AMP_LD(r);
  }
}

extern "C" void kernel_launch(void* const* d_in, const int* in_sizes, int n_in,
                              void* d_out, int out_size, void* d_ws, size_t ws_size,
                              hipStream_t stream) {
  const float* states = (const float*)d_in[0];  // (24, 2) f32
  const float* gates = (const float*)d_in[1];   // (46, 2,2,2,2) f32
  float* out = (float*)d_out;                   // 2^24 f32

  k_pass1<<<1024, 256, 0, stream>>>(states, gates, out);
  k_pass2a<<<1024, 256, 0, stream>>>(gates, out);
  k_pass2b<<<1024, 256, 0, stream>>>(gates, out);
}

// Round 5
// 188.931 us; speedup vs baseline: 1.3850x; 1.3850x over previous
//
#include <hip/hip_runtime.h>

// 24-qubit brickwork circuit, register-resident gates, 32KB split-LDS transposes.
// State: flat index i in [0, 2^24), wire w <-> bit (23-w).
// Gate on wires (w,w+1): p1 = 22-w, p0 = 23-w. M[v][u] = G[u0,v0,u1,v1],
// u = (u0<<1)|u1, u0 = bit p0, u1 = bit p1 (v likewise).
//
// Each thread holds 64 amps in PLAIN float v[64] (r4's v2f packing pushed the
// array into AGPRs -> accvgpr ping-pong -> 2x slowdown; r2's float[64] stayed
// in VGPRs at 88 count). Layout = assignment of 6 j-bits to reg bits r0..r5.
// Transitions: 2-stage transpose through an 8192-float LDS buffer, split on a
// j-bit that sits at the SAME reg position in both layouts (in-place safe).
// Bank bits = SWZ(j) bits 0..4 (split bits >=5 removed above them) -> all
// patterns <=2 lanes/bank (verified free, r2 measured 0 conflicts).

#define SWZ(j) ((j) ^ (((j) >> 6) & 15) ^ ((((j) >> 10) & 1) << 4))
#define DEL(x, S) (((x) & ((1 << (S)) - 1)) | (((x) >> ((S) + 1)) << (S)))

// Gate acting on reg bits B0 (holds p1 / u1) and B1 (holds p0 / u0).
template<int B0, int B1>
__device__ __forceinline__ void gate_sc(float v[64], const float* __restrict__ g) {
  float m[16];
#pragma unroll
  for (int vv = 0; vv < 4; ++vv)
#pragma unroll
    for (int uu = 0; uu < 4; ++uu)
      m[vv * 4 + uu] = g[(uu >> 1) * 8 + (vv >> 1) * 4 + (uu & 1) * 2 + (vv & 1)];
  constexpr int S1 = 1 << B0;  // u1 stride
  constexpr int S0 = 1 << B1;  // u0 stride
#pragma unroll
  for (int b = 0; b < 64; ++b) {
    if (b & (S0 | S1)) continue;
    const float a0 = v[b], a1 = v[b + S1], a2 = v[b + S0], a3 = v[b + S0 + S1];
    v[b]           = m[0]  * a0 + m[1]  * a1 + m[2]  * a2 + m[3]  * a3;
    v[b + S1]      = m[4]  * a0 + m[5]  * a1 + m[6]  * a2 + m[7]  * a3;
    v[b + S0]      = m[8]  * a0 + m[9]  * a1 + m[10] * a2 + m[11] * a3;
    v[b + S0 + S1] = m[12] * a0 + m[13] * a1 + m[14] * a2 + m[15] * a3;
  }
}

// layout formulas: j(t, r)
// pass1: B r=[j8..j13], t=j0..7
#define JB1(t, r) ((t) | ((r) << 8))
// pass1: M r=[j8,j4,j5,j6,j7,j9], t0..3=j0..3, t4..7=j10..13
#define JM1(t, r) (((t) & 15) | ((((r) >> 1) & 15) << 4) | (((r) & 1) << 8) | (((r) >> 5) << 9) | (((t) >> 4) << 10))
// pass1: A r=[j0,j1,j5,j2,j3,j4], t=j6..13
#define JA1(t, r) (((r) & 3) | ((((r) >> 3) & 7) << 2) | ((((r) >> 2) & 1) << 5) | ((t) << 6))
// pass1: W r=[j6,j7,j5,j8,j9,j10], t0..4=j0..4, t5..7=j11..13
#define JW1(t, r) (((t) & 31) | ((((r) >> 2) & 1) << 5) | (((r) & 1) << 6) | ((((r) >> 1) & 1) << 7) | ((((r) >> 3) & 7) << 8) | (((t) >> 5) << 11))
// pass2: F r=[j0,j1,j10,j11,j12,j13], t=j2..9
#define JF(t, r)  (((r) & 3) | ((t) << 2) | (((r) >> 2) << 10))
// pass2a: V r=[j7,j8,j10,j9,j11,j12], t0..6=j0..6, t7=j13
#define JV(t, r)  (((t) & 127) | (((r) & 1) << 7) | ((((r) >> 1) & 1) << 8) | ((((r) >> 3) & 1) << 9) | ((((r) >> 2) & 1) << 10) | ((((r) >> 4) & 3) << 11) | (((t) >> 7) << 13))
// pass2b: W r=[j8,j5,j6,j7,j9,j10], t0..4=j0..4, t5..7=j11..13
#define JW2(t, r) (((t) & 31) | ((((r) >> 1) & 7) << 5) | (((r) & 1) << 8) | ((((r) >> 4) & 3) << 9) | (((t) >> 5) << 11))

// 2-stage in-place transpose through 8192-float buf. Split j-bit S sits at
// reg position RBIT in BOTH layouts, so stage read-set == stage write-set.
#define TRANS(JW, JR, S, RBIT)                                        \
  do {                                                                \
    _Pragma("unroll")                                                 \
    for (int r = 0; r < 64; ++r) if ((((r) >> (RBIT)) & 1) == 0)      \
      buf[DEL(SWZ(JW(t, r)), S)] = v[r];                              \
    __syncthreads();                                                  \
    _Pragma("unroll")                                                 \
    for (int r = 0; r < 64; ++r) if ((((r) >> (RBIT)) & 1) == 0)      \
      v[r] = buf[DEL(SWZ(JR(t, r)), S)];                              \
    __syncthreads();                                                  \
    _Pragma("unroll")                                                 \
    for (int r = 0; r < 64; ++r) if ((((r) >> (RBIT)) & 1) == 1)      \
      buf[DEL(SWZ(JW(t, r)), S)] = v[r];                              \
    __syncthreads();                                                  \
    _Pragma("unroll")                                                 \
    for (int r = 0; r < 64; ++r) if ((((r) >> (RBIT)) & 1) == 1)      \
      v[r] = buf[DEL(SWZ(JR(t, r)), S)];                              \
    __syncthreads();                                                  \
  } while (0)

// ---------------- Pass 1: init + 24 gates on bits 0..13 (wires 10..23) -------
__global__ __launch_bounds__(256) void k_pass1(
    const float* __restrict__ states, const float* __restrict__ gates,
    float* __restrict__ out) {
  __shared__ float buf[8192];
  const int t = threadIdx.x;
  const int b = blockIdx.x;  // global bits 14..23 (wires 9..0)

  {
    float p = 1.f;
    for (int k = 0; k < 8; ++k) p *= states[(23 - k) * 2 + ((t >> k) & 1)];
    buf[t] = p;  // sLo over j0..7 (wires 23..16)
    if (t < 64) {
      float q = 1.f;
      for (int k = 0; k < 6; ++k) q *= states[(15 - k) * 2 + ((t >> k) & 1)];
      buf[256 + t] = q;  // sHi over j8..13 (wires 15..10)
    }
  }
  float pref = 1.f;
  for (int k = 0; k < 10; ++k) pref *= states[(9 - k) * 2 + ((b >> k) & 1)];
  __syncthreads();

  float v[64];
  const float plT = pref * buf[t];
#pragma unroll
  for (int r = 0; r < 64; ++r) v[r] = plT * buf[256 + r];  // B layout: r=j8..13
  __syncthreads();  // protect buf before transition writes

  // Phase B (r=[j8..13]): g5(12,13) g6(10,11) g7(8,9) g17(11,12) g18(9,10) g29(10,11)
  gate_sc<4, 5>(v, gates + 16 * 5);
  gate_sc<2, 3>(v, gates + 16 * 6);
  gate_sc<0, 1>(v, gates + 16 * 7);
  gate_sc<3, 4>(v, gates + 16 * 17);
  gate_sc<1, 2>(v, gates + 16 * 18);
  gate_sc<2, 3>(v, gates + 16 * 29);
  TRANS(JB1, JM1, 8, 0);  // split j8 @ r0
  // Phase M (r=[j8,j4,j5,j6,j7,j9]): g8(6,7) g9(4,5) g19(7,8) g20(5,6) g30(8,9) g31(6,7)
  gate_sc<3, 4>(v, gates + 16 * 8);
  gate_sc<1, 2>(v, gates + 16 * 9);
  gate_sc<4, 0>(v, gates + 16 * 19);
  gate_sc<2, 3>(v, gates + 16 * 20);
  gate_sc<0, 5>(v, gates + 16 * 30);
  gate_sc<3, 4>(v, gates + 16 * 31);
  TRANS(JM1, JA1, 5, 2);  // split j5 @ r2
  // Phase A (r=[j0,j1,j5,j2,j3,j4]): g10(2,3) g11(0,1) g21(3,4) g22(1,2)
  //                                   g32(4,5) g33(2,3) g34(0,1) g44(3,4) g45(1,2)
  gate_sc<3, 4>(v, gates + 16 * 10);
  gate_sc<0, 1>(v, gates + 16 * 11);
  gate_sc<4, 5>(v, gates + 16 * 21);
  gate_sc<1, 3>(v, gates + 16 * 22);
  gate_sc<5, 2>(v, gates + 16 * 32);
  gate_sc<3, 4>(v, gates + 16 * 33);
  gate_sc<0, 1>(v, gates + 16 * 34);
  gate_sc<4, 5>(v, gates + 16 * 44);
  gate_sc<1, 3>(v, gates + 16 * 45);
  TRANS(JA1, JW1, 5, 2);  // split j5 @ r2
  // Phase W (r=[j6,j7,j5,j8,j9,j10]): g41(9,10) g42(7,8) g43(5,6)
  gate_sc<4, 5>(v, gates + 16 * 41);
  gate_sc<1, 3>(v, gates + 16 * 42);
  gate_sc<2, 0>(v, gates + 16 * 43);

  const long long ob = ((long long)b) << 14;
#pragma unroll
  for (int r = 0; r < 64; ++r) out[ob | JW1(t, r)] = v[r];  // 2x128B runs/inst
}

// ---------------- Pass 2a: 8 gates, tile = global {0..5} u {10..17} ----------
// local j: j0..5 = global 0..5, j6..13 = global 10..17
__global__ __launch_bounds__(256) void k_pass2a(
    const float* __restrict__ gates, float* __restrict__ out) {
  __shared__ float buf[8192];
  const int t = threadIdx.x;
  const int b = blockIdx.x;
  const long long base0 = (((long long)(b >> 4)) << 18) | ((long long)(b & 15) << 6);

  float v[64];
#pragma unroll
  for (int c = 0; c < 16; ++c) {  // F layout load, 256B runs
    float4 x = *(const float4*)(&out[base0 + ((t & 15) << 2) + ((t >> 4) << 10) + ((long long)c << 14)]);
    v[4 * c] = x.x; v[4 * c + 1] = x.y; v[4 * c + 2] = x.z; v[4 * c + 3] = x.w;
  }
  // Phase F (r=[j0,j1,j10..13]): g3(12,13)
  gate_sc<4, 5>(v, gates + 16 * 3);
  TRANS(JF, JV, 10, 2);  // split j10 @ r2
  // Phase V (r=[j7,j8,j10,j9,j11,j12]): g4(10,11) g15(11,12) g16(9,10)
  //                                      g27(10,11) g28(8,9) g39(9,10) g40(7,8)
  gate_sc<2, 4>(v, gates + 16 * 4);
  gate_sc<4, 5>(v, gates + 16 * 15);
  gate_sc<3, 2>(v, gates + 16 * 16);
  gate_sc<2, 4>(v, gates + 16 * 27);
  gate_sc<1, 3>(v, gates + 16 * 28);
  gate_sc<3, 2>(v, gates + 16 * 39);
  gate_sc<0, 1>(v, gates + 16 * 40);

#pragma unroll
  for (int r = 0; r < 64; ++r) {  // V-layout store, 256B runs
    const int j = JV(t, r);
    out[base0 | (((long long)(j >> 6)) << 10) | (j & 63)] = v[r];
  }
}

// ---------------- Pass 2b: 14 gates, tile = global {0..4} u {15..23} ---------
// local j: j0..4 = global 0..4, j5..13 = global 15..23
__global__ __launch_bounds__(256) void k_pass2b(
    const float* __restrict__ gates, float* __restrict__ out) {
  __shared__ float buf[8192];
  const int t = threadIdx.x;
  const int b = blockIdx.x;  // global bits 5..14

  float v[64];
#pragma unroll
  for (int c = 0; c < 16; ++c) {  // F layout load, 128B runs
    float4 x = *(const float4*)(&out[((t & 7) << 2) + ((long long)b << 5) + ((t >> 3) << 15) + ((long long)c << 20)]);
    v[4 * c] = x.x; v[4 * c + 1] = x.y; v[4 * c + 2] = x.z; v[4 * c + 3] = x.w;
  }
  // Phase F (r=[j0,j1,j10..13]): g0(12,13) g1(10,11) g12(11,12) g23(12,13)
  gate_sc<4, 5>(v, gates + 16 * 0);
  gate_sc<2, 3>(v, gates + 16 * 1);
  gate_sc<3, 4>(v, gates + 16 * 12);
  gate_sc<4, 5>(v, gates + 16 * 23);
  TRANS(JF, JB1, 10, 2);  // split j10 @ r2
  // Phase B (r=[j8..13]): g2(8,9) g13(9,10) g24(10,11) g35(11,12)
  gate_sc<0, 1>(v, gates + 16 * 2);
  gate_sc<1, 2>(v, gates + 16 * 13);
  gate_sc<2, 3>(v, gates + 16 * 24);
  gate_sc<3, 4>(v, gates + 16 * 35);
  TRANS(JB1, JW2, 8, 0);  // split j8 @ r0
  // Phase W (r=[j8,j5,j6,j7,j9,j10]): g14(7,8) g25(8,9) g26(6,7)
  //                                    g36(9,10) g37(7,8) g38(5,6)
  gate_sc<3, 0>(v, gates + 16 * 14);
  gate_sc<0, 4>(v, gates + 16 * 25);
  gate_sc<2, 3>(v, gates + 16 * 26);
  gate_sc<4, 5>(v, gates + 16 * 36);
  gate_sc<3, 0>(v, gates + 16 * 37);
  gate_sc<1, 2>(v, gates + 16 * 38);

#pragma unroll
  for (int r = 0; r < 64; ++r) {  // W-layout store, 2x128B runs/inst
    const int j = JW2(t, r);
    out[(((long long)(j >> 5)) << 15) | ((long long)b << 5) | (j & 31)] = v[r];
  }
}

extern "C" void kernel_launch(void* const* d_in, const int* in_sizes, int n_in,
                              void* d_out, int out_size, void* d_ws, size_t ws_size,
                              hipStream_t stream) {
  const float* states = (const float*)d_in[0];  // (24, 2) f32
  const float* gates = (const float*)d_in[1];   // (46, 2,2,2,2) f32
  float* out = (float*)d_out;                   // 2^24 f32

  k_pass1<<<1024, 256, 0, stream>>>(states, gates, out);
  k_pass2a<<<1024, 256, 0, stream>>>(gates, out);
  k_pass2b<<<1024, 256, 0, stream>>>(gates, out);
}